// Round 12
// baseline (735.785 us; speedup 1.0000x reference)
//
#include <hip/hip_runtime.h>
#include <stdint.h>

#define DIMK 1024
#define HID  2816

typedef __attribute__((ext_vector_type(8))) __bf16 bf16x8;
typedef __attribute__((ext_vector_type(4))) float  f32x4;

typedef const __attribute__((address_space(1))) void* gas1_t;
typedef __attribute__((address_space(3))) void*       las3_t;

__device__ __forceinline__ uint16_t f2bf(float f) {
  uint32_t u = __float_as_uint(f);
  u += 0x7FFFu + ((u >> 16) & 1u);   // round-to-nearest-even
  return (uint16_t)(u >> 16);
}

__device__ __forceinline__ void gload16(const uint16_t* g, uint16_t* l) {
  __builtin_amdgcn_global_load_lds((gas1_t)g, (las3_t)l, 16, 0, 0);
}

template<int N> __device__ __forceinline__ void wait_vm() {
  if constexpr (N == 0)      asm volatile("s_waitcnt vmcnt(0)" ::: "memory");
  else if constexpr (N == 2) asm volatile("s_waitcnt vmcnt(2)" ::: "memory");
  else if constexpr (N == 4) asm volatile("s_waitcnt vmcnt(4)" ::: "memory");
}

// Stage one 128x64 bf16 half-tile (16 KB, 2 global_load_lds/thread). LDS dest
// LINEAR (global_load_lds constraint); XOR swizzle realized by permuting the
// GLOBAL source granule: slot (row, s) receives global granule s ^ (row&7).
__device__ __forceinline__ void stage_half(const uint16_t* g, long stride,
                                           uint16_t* lds, int wv, int lane) {
  const int rsub = lane >> 3;                 // row within 8-row block
  const int gsw  = ((lane & 7) ^ rsub) << 3;  // inverse-swizzled source granule (elems)
#pragma unroll
  for (int j = 0; j < 2; ++j) {
    const int blk = j * 8 + wv;               // 16 blocks x 8 rows = 128 rows
    gload16(g + (long)(blk * 8 + rsub) * stride + gsw,
            lds + blk * 512 + lane * 8);
  }
}

// Swizzled fragment read: logical (row r, 16B-granule g) lives at slot g^(r&7).
// Conflict-free for 16-row read groups (measured 0; 32-row groups 4-way - R9).
__device__ __forceinline__ bf16x8 ldsf(const uint16_t* lds, int r, int g) {
  return *reinterpret_cast<const bf16x8*>(lds + r * 64 + ((g ^ (r & 7)) << 3));
}

// ---- slot assignment: count -> scan -> rank (no contended atomics) ----

__global__ void count_kernel(const int* __restrict__ mids, int* __restrict__ bc, int T) {
  const int b = blockIdx.x, t = threadIdx.x;
  const int token = b * 256 + t;
  const int lane = t & 63, wv = t >> 6;
  const int m = (token < T) ? mids[token] : -1;
  unsigned long long m0 = __ballot(m == 0);
  unsigned long long m1 = __ballot(m == 1);
  __shared__ int w0[4], w1[4];
  if (lane == 0) { w0[wv] = __popcll(m0); w1[wv] = __popcll(m1); }
  __syncthreads();
  if (t == 0) {
    bc[2 * b]     = w0[0] + w0[1] + w0[2] + w0[3];
    bc[2 * b + 1] = w1[0] + w1[1] + w1[2] + w1[3];
  }
}

__global__ void scan_kernel(const int* __restrict__ bc, int* __restrict__ base,
                            int* __restrict__ counters, int nb) {
  __shared__ int s0[256], s1[256];
  const int t = threadIdx.x;
  const int v0 = (t < nb) ? bc[2 * t] : 0;
  const int v1 = (t < nb) ? bc[2 * t + 1] : 0;
  s0[t] = v0; s1[t] = v1;
  __syncthreads();
  for (int off = 1; off < 256; off <<= 1) {
    int a0 = (t >= off) ? s0[t - off] : 0;
    int a1 = (t >= off) ? s1[t - off] : 0;
    __syncthreads();
    s0[t] += a0; s1[t] += a1;
    __syncthreads();
  }
  if (t < nb) { base[2 * t] = s0[t] - v0; base[2 * t + 1] = s1[t] - v1; }
  if (t == nb - 1) { counters[0] = s0[t]; counters[1] = s1[t]; }
}

__global__ void slot_kernel(const int* __restrict__ mids, const int* __restrict__ base,
                            const int* __restrict__ counters, int* __restrict__ tok,
                            int* __restrict__ slotof, int T) {
  const int b = blockIdx.x, t = threadIdx.x;
  const int token = b * 256 + t;
  const int lane = t & 63, wv = t >> 6;
  const int m = (token < T) ? mids[token] : -1;
  unsigned long long m0 = __ballot(m == 0);
  unsigned long long m1 = __ballot(m == 1);
  __shared__ int w0[4], w1[4];
  if (lane == 0) { w0[wv] = __popcll(m0); w1[wv] = __popcll(m1); }
  __syncthreads();
  int pre0 = 0, pre1 = 0;
  for (int w = 0; w < wv; ++w) { pre0 += w0[w]; pre1 += w1[w]; }
  if (token >= T) return;
  const unsigned long long below = (1ULL << lane) - 1ULL;
  const int c0 = counters[0];
  const int al0 = ((c0 + 255) >> 8) << 8;      // modality-1 region starts 256-tile-aligned
  int slot;
  if (m == 0) slot = base[2 * b] + pre0 + __popcll(m0 & below);
  else        slot = al0 + base[2 * b + 1] + pre1 + __popcll(m1 & below);
  tok[slot] = token;
  slotof[token] = slot;
}

__global__ void copy_kernel(const float* __restrict__ x, const int* __restrict__ slotof,
                            uint16_t* __restrict__ xg, int T) {
  const int token = blockIdx.x * 4 + (threadIdx.x >> 6);
  if (token >= T) return;
  const int lane = threadIdx.x & 63;
  const int slot = slotof[token];
  const float4* src = (const float4*)(x + (long)token * DIMK);
  uint16_t* dst = xg + (long)slot * DIMK;
#pragma unroll
  for (int j = 0; j < 4; ++j) {
    float4 v = src[lane + 64 * j];
    ushort4 o;
    o.x = f2bf(v.x); o.y = f2bf(v.y); o.z = f2bf(v.z); o.w = f2bf(v.w);
    *(ushort4*)(dst + (lane + 64 * j) * 4) = o;
  }
}

// single launch converting all three weight tensors fp32 -> bf16
__global__ void convert3_kernel(const float* __restrict__ s0, const float* __restrict__ s1,
                                const float* __restrict__ s2, uint16_t* __restrict__ d0,
                                uint16_t* __restrict__ d1, uint16_t* __restrict__ d2,
                                long n, int cblk) {
  const int seg = blockIdx.x / cblk;
  const int bid = blockIdx.x - seg * cblk;
  const float* src = (seg == 0) ? s0 : (seg == 1) ? s1 : s2;
  uint16_t*    dst = (seg == 0) ? d0 : (seg == 1) ? d1 : d2;
  long i = ((long)bid * blockDim.x + threadIdx.x) * 4;
  if (i >= n) return;
  float4 v = *(const float4*)(src + i);
  ushort4 o;
  o.x = f2bf(v.x); o.y = f2bf(v.y); o.z = f2bf(v.z); o.w = f2bf(v.w);
  *(ushort4*)(dst + i) = o;
}

// ------------- shared quad-tile: 256xM rows A, dual 128-col B (Bx,By) -------------
// R10 schedule with intra-phase pins REMOVED. Per K-tile: 4 phases, each =
// {wait vmcnt (counted), s_barrier, compiler fence, ds_reads + 1 half-tile
// stage + 16 MFMA with NO lgkmcnt(0)/sched_barrier/setprio between them} —
// the compiler emits counted lgkmcnt(N) so ds_reads of frag k+1 overlap MFMAs
// of frag k (m97 mechanism; m141: full pinning costs ~40%). Barriers + counted
// vmcnt keep waves/blocks lockstep (R8 showed losing this thrashes L2/L3).
// One lgkmcnt(0) at K-tile END drains the read queue before the next tile's
// stages may overwrite the buffer just read (correctness boundary).

template<bool PF, int W0, int W1, int W2>
__device__ __forceinline__ void quad_tile(
    const uint16_t* Ac, const uint16_t* Bxc, const uint16_t* Byc,
    uint16_t* An, uint16_t* Bxn, uint16_t* Byn,
    const uint16_t* gA, const uint16_t* gBx, const uint16_t* gBy,
    long ko, long stride,
    int wv, int lane, int wr, int wc, int lrow, int grp,
    f32x4 (&accX)[8][2], f32x4 (&accY)[8][2]) {
  bf16x8 a[4][2], bx[2][2], by[2][2];
  // ---- ph0: X-low | reads Alo(8)+Bx(4) | stage Alo(t+1)
  wait_vm<W0>();
  __builtin_amdgcn_s_barrier();
  asm volatile("" ::: "memory");
#pragma unroll
  for (int m = 0; m < 4; ++m) {
    a[m][0] = ldsf(Ac, m * 32 + wr * 16 + lrow, grp);
    a[m][1] = ldsf(Ac, m * 32 + wr * 16 + lrow, 4 + grp);
  }
#pragma unroll
  for (int n = 0; n < 2; ++n) {
    bx[n][0] = ldsf(Bxc, wc * 32 + n * 16 + lrow, grp);
    bx[n][1] = ldsf(Bxc, wc * 32 + n * 16 + lrow, 4 + grp);
  }
  if constexpr (PF) stage_half(gA + ko, stride, An, wv, lane);
#pragma unroll
  for (int ks = 0; ks < 2; ++ks)
#pragma unroll
    for (int m = 0; m < 4; ++m)
#pragma unroll
      for (int n = 0; n < 2; ++n)
        accX[m][n] = __builtin_amdgcn_mfma_f32_16x16x32_bf16(a[m][ks], bx[n][ks], accX[m][n], 0, 0, 0);
  // ---- ph1: Y-low | reads By(4) | stage Bx(t+1)
  wait_vm<W1>();
  __builtin_amdgcn_s_barrier();
  asm volatile("" ::: "memory");
#pragma unroll
  for (int n = 0; n < 2; ++n) {
    by[n][0] = ldsf(Byc, wc * 32 + n * 16 + lrow, grp);
    by[n][1] = ldsf(Byc, wc * 32 + n * 16 + lrow, 4 + grp);
  }
  if constexpr (PF) stage_half(gBx + ko, stride, Bxn, wv, lane);
#pragma unroll
  for (int ks = 0; ks < 2; ++ks)
#pragma unroll
    for (int m = 0; m < 4; ++m)
#pragma unroll
      for (int n = 0; n < 2; ++n)
        accY[m][n] = __builtin_amdgcn_mfma_f32_16x16x32_bf16(a[m][ks], by[n][ks], accY[m][n], 0, 0, 0);
  // ---- ph2: X-high | reads Ahi(8) | stage By(t+1)
  wait_vm<W2>();
  __builtin_amdgcn_s_barrier();
  asm volatile("" ::: "memory");
#pragma unroll
  for (int m = 0; m < 4; ++m) {
    a[m][0] = ldsf(Ac, (m + 4) * 32 + wr * 16 + lrow, grp);
    a[m][1] = ldsf(Ac, (m + 4) * 32 + wr * 16 + lrow, 4 + grp);
  }
  if constexpr (PF) stage_half(gBy + ko, stride, Byn, wv, lane);
#pragma unroll
  for (int ks = 0; ks < 2; ++ks)
#pragma unroll
    for (int m = 0; m < 4; ++m)
#pragma unroll
      for (int n = 0; n < 2; ++n)
        accX[m + 4][n] = __builtin_amdgcn_mfma_f32_16x16x32_bf16(a[m][ks], bx[n][ks], accX[m + 4][n], 0, 0, 0);
  // ---- ph3: Y-high | no reads | stage Ahi(t+1) (operands all in regs)
  if constexpr (PF) stage_half(gA + 128 * stride + ko, stride, An + 128 * 64, wv, lane);
#pragma unroll
  for (int ks = 0; ks < 2; ++ks)
#pragma unroll
    for (int m = 0; m < 4; ++m)
#pragma unroll
      for (int n = 0; n < 2; ++n)
        accY[m + 4][n] = __builtin_amdgcn_mfma_f32_16x16x32_bf16(a[m][ks], by[n][ks], accY[m + 4][n], 0, 0, 0);
  // K-tile-end drain: all ds_reads of this tile's buffers retired before any
  // wave crosses the next barrier and overwrites them via global_load_lds.
  asm volatile("s_waitcnt lgkmcnt(0)" ::: "memory");
}

// ---------------- GEMM1: 256x128 tile, dual-B (W1,W3) ----------------

__global__ __launch_bounds__(512, 2) void gemm1_kernel(
    const uint16_t* __restrict__ xg, const uint16_t* __restrict__ w1b,
    const uint16_t* __restrict__ w3b, uint16_t* __restrict__ hbuf,
    const int* __restrict__ counters) {
  __shared__ __align__(16) uint16_t lsA[2][256 * 64];    // 64 KB
  __shared__ __align__(16) uint16_t lsB1[2][128 * 64];   // 32 KB
  __shared__ __align__(16) uint16_t lsB3[2][128 * 64];   // 32 KB

  const int c0 = counters[0], c1 = counters[1];
  const int t0 = (c0 + 255) >> 8, t1 = (c1 + 255) >> 8;
  // bijective XCD swizzle (m204): within an XCD chunk rt varies fastest ->
  // the B1/B3 128-col panels stay L2-resident per XCD (R5's measured config).
  const int GX = gridDim.x;
  const int nwg = GX * (int)gridDim.y;
  const int orig = blockIdx.y * GX + blockIdx.x;
  const int q = nwg >> 3, r = nwg & 7;
  const int xcd = orig & 7, loc = orig >> 3;
  const int swz = (xcd < r ? xcd * (q + 1) : r * (q + 1) + (xcd - r) * q) + loc;
  const int ht = swz / GX;
  const int rt = swz - ht * GX;
  if (rt >= t0 + t1) return;
  const int mod = (rt < t0) ? 0 : 1;
  const long row0 = (long)rt * 256;

  const int tid = threadIdx.x, lane = tid & 63, wv = tid >> 6;
  const int wr = wv >> 2, wc = wv & 3;            // 2M x 4N waves
  const int lrow = lane & 15, grp = lane >> 4;

  const uint16_t* gA  = xg  + row0 * DIMK;
  const uint16_t* gB1 = w1b + ((long)mod * HID + ht * 128) * DIMK;
  const uint16_t* gB3 = w3b + ((long)mod * HID + ht * 128) * DIMK;

  f32x4 accG[8][2], accU[8][2];
#pragma unroll
  for (int m = 0; m < 8; ++m)
#pragma unroll
    for (int n = 0; n < 2; ++n) {
      accG[m][n] = {0.f, 0.f, 0.f, 0.f};
      accU[m][n] = {0.f, 0.f, 0.f, 0.f};
    }

  // prologue: tile 0 -> buf 0, in issue order [Alo, B1, B3, Ahi]; no drain.
  stage_half(gA,              DIMK, &lsA[0][0],         wv, lane);
  stage_half(gB1,             DIMK, &lsB1[0][0],        wv, lane);
  stage_half(gB3,             DIMK, &lsB3[0][0],        wv, lane);
  stage_half(gA + 128 * DIMK, DIMK, &lsA[0][128 * 64],  wv, lane);

  const int NT = DIMK / 64;                        // 16
  int cur = 0;
  for (int t = 0; t < NT - 1; ++t) {
    quad_tile<true, 4, 4, 4>(&lsA[cur][0], &lsB1[cur][0], &lsB3[cur][0],
                             &lsA[cur ^ 1][0], &lsB1[cur ^ 1][0], &lsB3[cur ^ 1][0],
                             gA, gB1, gB3, (long)(t + 1) * 64, DIMK,
                             wv, lane, wr, wc, lrow, grp, accG, accU);
    cur ^= 1;
  }
  quad_tile<false, 4, 2, 0>(&lsA[cur][0], &lsB1[cur][0], &lsB3[cur][0],
                            &lsA[cur ^ 1][0], &lsB1[cur ^ 1][0], &lsB3[cur ^ 1][0],
                            gA, gB1, gB3, 0, DIMK,
                            wv, lane, wr, wc, lrow, grp, accG, accU);

  // epilogue: h = silu(x1) * x3 -> bf16 (gap rows harmless, never scattered)
#pragma unroll
  for (int m = 0; m < 8; ++m)
#pragma unroll
    for (int n = 0; n < 2; ++n) {
      const int col = ht * 128 + wc * 32 + n * 16 + lrow;
#pragma unroll
      for (int i = 0; i < 4; ++i) {
        const long row = row0 + m * 32 + wr * 16 + grp * 4 + i;
        float g = accG[m][n][i];
        float u = accU[m][n][i];
        float hv = (g / (1.f + __expf(-g))) * u;
        hbuf[row * HID + col] = f2bf(hv);
      }
    }
}

// ---------------- GEMM2: 256x256 tile via the same quad-tile ----------------
// Bx = W2 rows ct*256..+127, By = rows +128..255; accY cols offset +128.

__global__ __launch_bounds__(512, 2) void gemm2_kernel(
    const uint16_t* __restrict__ hbuf, const uint16_t* __restrict__ w2b,
    const int* __restrict__ counters, const int* __restrict__ tok,
    float* __restrict__ out) {
  __shared__ __align__(16) uint16_t lsA[2][256 * 64];    // 64 KB
  __shared__ __align__(16) uint16_t lsBx[2][128 * 64];   // 32 KB
  __shared__ __align__(16) uint16_t lsBy[2][128 * 64];   // 32 KB

  const int c0 = counters[0], c1 = counters[1];
  const int t0 = (c0 + 255) >> 8, t1 = (c1 + 255) >> 8;
  // rt-major chunks: same-XCD blocks share the A (hbuf) row-tile in L2.
  const int NCT = gridDim.y;                       // 4
  const int nwg = gridDim.x * NCT;
  const int orig = blockIdx.y * gridDim.x + blockIdx.x;
  const int q = nwg >> 3, r = nwg & 7;
  const int xcd = orig & 7, loc = orig >> 3;
  const int swz = (xcd < r ? xcd * (q + 1) : r * (q + 1) + (xcd - r) * q) + loc;
  const int rt = swz / NCT;
  const int ct = swz - rt * NCT;
  if (rt >= t0 + t1) return;
  const int mod = (rt < t0) ? 0 : 1;
  const long row0 = (long)rt * 256;
  const int vlimit = (mod == 0) ? c0 : t0 * 256 + c1;

  const int tid = threadIdx.x, lane = tid & 63, wv = tid >> 6;
  const int wr = wv >> 2, wc = wv & 3;
  const int lrow = lane & 15, grp = lane >> 4;

  const uint16_t* gA  = hbuf + row0 * HID;
  const uint16_t* gBx = w2b + ((long)mod * DIMK + ct * 256) * HID;
  const uint16_t* gBy = gBx + 128 * HID;

  f32x4 accX[8][2], accY[8][2];
#pragma unroll
  for (int m = 0; m < 8; ++m)
#pragma unroll
    for (int n = 0; n < 2; ++n) {
      accX[m][n] = {0.f, 0.f, 0.f, 0.f};
      accY[m][n] = {0.f, 0.f, 0.f, 0.f};
    }

  // prologue: tile 0 -> buf 0, issue order [Alo, Bx, By, Ahi]
  stage_half(gA,             HID, &lsA[0][0],        wv, lane);
  stage_half(gBx,            HID, &lsBx[0][0],       wv, lane);
  stage_half(gBy,            HID, &lsBy[0][0],       wv, lane);
  stage_half(gA + 128 * HID, HID, &lsA[0][128 * 64], wv, lane);

  const int NT = HID / 64;                         // 44
  int cur = 0;
  for (int t = 0; t < NT - 1; ++t) {
    quad_tile<true, 4, 4, 4>(&lsA[cur][0], &lsBx[cur][0], &lsBy[cur][0],
                             &lsA[cur ^ 1][0], &lsBx[cur ^ 1][0], &lsBy[cur ^ 1][0],
                             gA, gBx, gBy, (long)(t + 1) * 64, HID,
                             wv, lane, wr, wc, lrow, grp, accX, accY);
    cur ^= 1;
  }
  quad_tile<false, 4, 2, 0>(&lsA[cur][0], &lsBx[cur][0], &lsBy[cur][0],
                            &lsA[cur ^ 1][0], &lsBx[cur ^ 1][0], &lsBy[cur ^ 1][0],
                            gA, gBx, gBy, 0, HID,
                            wv, lane, wr, wc, lrow, grp, accX, accY);

#pragma unroll
  for (int m = 0; m < 8; ++m)
#pragma unroll
    for (int n = 0; n < 2; ++n) {
      const int colX = ct * 256 + wc * 32 + n * 16 + lrow;
#pragma unroll
      for (int i = 0; i < 4; ++i) {
        const int row = (int)row0 + m * 32 + wr * 16 + grp * 4 + i;
        if (row < vlimit) {
          const long obase = (long)tok[row] * DIMK;
          out[obase + colX]       = accX[m][n][i];
          out[obase + colX + 128] = accY[m][n][i];
        }
      }
    }
}

extern "C" void kernel_launch(void* const* d_in, const int* in_sizes, int n_in,
                              void* d_out, int out_size, void* d_ws, size_t ws_size,
                              hipStream_t stream) {
  const float* x    = (const float*)d_in[0];
  const int*   mids = (const int*)d_in[1];
  const float* W1   = (const float*)d_in[2];
  const float* W2   = (const float*)d_in[3];
  const float* W3   = (const float*)d_in[4];
  float* out = (float*)d_out;

  const int T   = in_sizes[1];                       // 32768 tokens
  const int NB  = (T + 255) / 256;                   // 128 count blocks
  const int CAP = ((T + 255) & ~255) + 256;          // 256-aligned capacity + gap tile

  char* ws = (char*)d_ws;
  int* counters = (int*)ws;                          // [c0, c1]
  int* bc   = (int*)(ws + 256);                      // per-block counts [NB][2]
  int* base = (int*)(ws + 256 + 2048);               // per-block bases  [NB][2]
  int* tok  = (int*)(ws + 256 + 4096);               // slot -> token
  int* slotof = tok + ((CAP + 63) & ~63);            // token -> slot
  size_t off = 256 + 4096 + (size_t)((CAP + 63) & ~63) * 4 + (size_t)((T + 63) & ~63) * 4;
  off = (off + 255) & ~(size_t)255;
  uint16_t* xg  = (uint16_t*)(ws + off); off += (size_t)CAP * DIMK * 2;
  uint16_t* w1b = (uint16_t*)(ws + off); off += (size_t)2 * HID * DIMK * 2;
  uint16_t* w3b = (uint16_t*)(ws + off); off += (size_t)2 * HID * DIMK * 2;
  uint16_t* w2b = (uint16_t*)(ws + off); off += (size_t)2 * DIMK * HID * 2;
  uint16_t* hbuf = (uint16_t*)(ws + off); off += (size_t)CAP * HID * 2;
  (void)ws_size; (void)n_in; (void)out_size;

  count_kernel<<<NB, 256, 0, stream>>>(mids, bc, T);
  scan_kernel<<<1, 256, 0, stream>>>(bc, base, counters, NB);
  slot_kernel<<<NB, 256, 0, stream>>>(mids, base, counters, tok, slotof, T);
  copy_kernel<<<(T + 3) / 4, 256, 0, stream>>>(x, slotof, xg, T);

  const long NW = (long)2 * HID * DIMK;              // elements per weight tensor
  const int cblk = (int)((NW / 4 + 255) / 256);
  convert3_kernel<<<3 * cblk, 256, 0, stream>>>(W1, W3, W2, w1b, w3b, w2b, NW, cblk);

  const int rtiles = CAP / 256;                      // 129
  gemm1_kernel<<<dim3(rtiles, HID / 128), 512, 0, stream>>>(xg, w1b, w3b, hbuf, counters);
  gemm2_kernel<<<dim3(rtiles, DIMK / 256), 512, 0, stream>>>(hbuf, w2b, counters, tok, out);
}

// Round 13
// 698.860 us; speedup vs baseline: 1.0528x; 1.0528x over previous
//
#include <hip/hip_runtime.h>
#include <stdint.h>

#define DIMK 1024
#define HID  2816

typedef __attribute__((ext_vector_type(8))) __bf16 bf16x8;
typedef __attribute__((ext_vector_type(4))) float  f32x4;

typedef const __attribute__((address_space(1))) void* gas1_t;
typedef __attribute__((address_space(3))) void*       las3_t;

__device__ __forceinline__ uint16_t f2bf(float f) {
  uint32_t u = __float_as_uint(f);
  u += 0x7FFFu + ((u >> 16) & 1u);   // round-to-nearest-even
  return (uint16_t)(u >> 16);
}

__device__ __forceinline__ void gload16(const uint16_t* g, uint16_t* l) {
  __builtin_amdgcn_global_load_lds((gas1_t)g, (las3_t)l, 16, 0, 0);
}

template<int N> __device__ __forceinline__ void wait_vm() {
  if constexpr (N == 0)      asm volatile("s_waitcnt vmcnt(0)" ::: "memory");
  else if constexpr (N == 2) asm volatile("s_waitcnt vmcnt(2)" ::: "memory");
  else if constexpr (N == 4) asm volatile("s_waitcnt vmcnt(4)" ::: "memory");
}

// Stage one 128x64 bf16 half-tile (16 KB, 2 global_load_lds/thread). LDS dest
// LINEAR (global_load_lds constraint); XOR swizzle realized by permuting the
// GLOBAL source granule: slot (row, s) receives global granule s ^ (row&7).
__device__ __forceinline__ void stage_half(const uint16_t* g, long stride,
                                           uint16_t* lds, int wv, int lane) {
  const int rsub = lane >> 3;                 // row within 8-row block
  const int gsw  = ((lane & 7) ^ rsub) << 3;  // inverse-swizzled source granule (elems)
#pragma unroll
  for (int j = 0; j < 2; ++j) {
    const int blk = j * 8 + wv;               // 16 blocks x 8 rows = 128 rows
    gload16(g + (long)(blk * 8 + rsub) * stride + gsw,
            lds + blk * 512 + lane * 8);
  }
}

// Swizzled fragment read: logical (row r, 16B-granule g) lives at slot g^(r&7).
// Conflict-free for 16-row read groups (measured 0; 32-row groups 4-way - R9).
__device__ __forceinline__ bf16x8 ldsf(const uint16_t* lds, int r, int g) {
  return *reinterpret_cast<const bf16x8*>(lds + r * 64 + ((g ^ (r & 7)) << 3));
}

// ---- slot assignment: count -> scan -> rank (no contended atomics) ----

__global__ void count_kernel(const int* __restrict__ mids, int* __restrict__ bc, int T) {
  const int b = blockIdx.x, t = threadIdx.x;
  const int token = b * 256 + t;
  const int lane = t & 63, wv = t >> 6;
  const int m = (token < T) ? mids[token] : -1;
  unsigned long long m0 = __ballot(m == 0);
  unsigned long long m1 = __ballot(m == 1);
  __shared__ int w0[4], w1[4];
  if (lane == 0) { w0[wv] = __popcll(m0); w1[wv] = __popcll(m1); }
  __syncthreads();
  if (t == 0) {
    bc[2 * b]     = w0[0] + w0[1] + w0[2] + w0[3];
    bc[2 * b + 1] = w1[0] + w1[1] + w1[2] + w1[3];
  }
}

__global__ void scan_kernel(const int* __restrict__ bc, int* __restrict__ base,
                            int* __restrict__ counters, int nb) {
  __shared__ int s0[256], s1[256];
  const int t = threadIdx.x;
  const int v0 = (t < nb) ? bc[2 * t] : 0;
  const int v1 = (t < nb) ? bc[2 * t + 1] : 0;
  s0[t] = v0; s1[t] = v1;
  __syncthreads();
  for (int off = 1; off < 256; off <<= 1) {
    int a0 = (t >= off) ? s0[t - off] : 0;
    int a1 = (t >= off) ? s1[t - off] : 0;
    __syncthreads();
    s0[t] += a0; s1[t] += a1;
    __syncthreads();
  }
  if (t < nb) { base[2 * t] = s0[t] - v0; base[2 * t + 1] = s1[t] - v1; }
  if (t == nb - 1) { counters[0] = s0[t]; counters[1] = s1[t]; }
}

__global__ void slot_kernel(const int* __restrict__ mids, const int* __restrict__ base,
                            const int* __restrict__ counters, int* __restrict__ tok,
                            int* __restrict__ slotof, int T) {
  const int b = blockIdx.x, t = threadIdx.x;
  const int token = b * 256 + t;
  const int lane = t & 63, wv = t >> 6;
  const int m = (token < T) ? mids[token] : -1;
  unsigned long long m0 = __ballot(m == 0);
  unsigned long long m1 = __ballot(m == 1);
  __shared__ int w0[4], w1[4];
  if (lane == 0) { w0[wv] = __popcll(m0); w1[wv] = __popcll(m1); }
  __syncthreads();
  int pre0 = 0, pre1 = 0;
  for (int w = 0; w < wv; ++w) { pre0 += w0[w]; pre1 += w1[w]; }
  if (token >= T) return;
  const unsigned long long below = (1ULL << lane) - 1ULL;
  const int c0 = counters[0];
  const int al0 = ((c0 + 255) >> 8) << 8;      // modality-1 region starts 256-tile-aligned
  int slot;
  if (m == 0) slot = base[2 * b] + pre0 + __popcll(m0 & below);
  else        slot = al0 + base[2 * b + 1] + pre1 + __popcll(m1 & below);
  tok[slot] = token;
  slotof[token] = slot;
}

__global__ void copy_kernel(const float* __restrict__ x, const int* __restrict__ slotof,
                            uint16_t* __restrict__ xg, int T) {
  const int token = blockIdx.x * 4 + (threadIdx.x >> 6);
  if (token >= T) return;
  const int lane = threadIdx.x & 63;
  const int slot = slotof[token];
  const float4* src = (const float4*)(x + (long)token * DIMK);
  uint16_t* dst = xg + (long)slot * DIMK;
#pragma unroll
  for (int j = 0; j < 4; ++j) {
    float4 v = src[lane + 64 * j];
    ushort4 o;
    o.x = f2bf(v.x); o.y = f2bf(v.y); o.z = f2bf(v.z); o.w = f2bf(v.w);
    *(ushort4*)(dst + (lane + 64 * j) * 4) = o;
  }
}

// single launch converting all three weight tensors fp32 -> bf16
__global__ void convert3_kernel(const float* __restrict__ s0, const float* __restrict__ s1,
                                const float* __restrict__ s2, uint16_t* __restrict__ d0,
                                uint16_t* __restrict__ d1, uint16_t* __restrict__ d2,
                                long n, int cblk) {
  const int seg = blockIdx.x / cblk;
  const int bid = blockIdx.x - seg * cblk;
  const float* src = (seg == 0) ? s0 : (seg == 1) ? s1 : s2;
  uint16_t*    dst = (seg == 0) ? d0 : (seg == 1) ? d1 : d2;
  long i = ((long)bid * blockDim.x + threadIdx.x) * 4;
  if (i >= n) return;
  float4 v = *(const float4*)(src + i);
  ushort4 o;
  o.x = f2bf(v.x); o.y = f2bf(v.y); o.z = f2bf(v.z); o.w = f2bf(v.w);
  *(ushort4*)(dst + i) = o;
}

// ------------- shared quad-tile: 256xM rows A, dual 128-col B (Bx,By) -------------
// The measured-best (R5/R10, 702us total) 4-phase schedule. Per K-tile: 4
// phases, each = {wait vmcnt, barrier, ds_reads, stage 1 half-tile, lgkm0,
// sched_barrier, setprio(1), 16 MFMA, setprio(0)}. Half-tile stage order
// [Alo,Bx,By,Ahi]; waits (4,4,4,-) force completion of loads issued exactly
// one K-tile earlier; never vmcnt(0) in main loop.
// gemm1: Bx=W1-tile, By=W3-tile (accX=gate, accY=up, same output cols).
// gemm2: Bx=B rows 0-127, By=B rows 128-255 (accY cols offset +128).

template<bool PF, int W0, int W1, int W2>
__device__ __forceinline__ void quad_tile(
    const uint16_t* Ac, const uint16_t* Bxc, const uint16_t* Byc,
    uint16_t* An, uint16_t* Bxn, uint16_t* Byn,
    const uint16_t* gA, const uint16_t* gBx, const uint16_t* gBy,
    long ko, long stride,
    int wv, int lane, int wr, int wc, int lrow, int grp,
    f32x4 (&accX)[8][2], f32x4 (&accY)[8][2]) {
  bf16x8 a[4][2], bx[2][2], by[2][2];
  // ---- ph0: X-low | reads Alo(8)+Bx(4) | stage Alo(t+1)
  wait_vm<W0>();
  __builtin_amdgcn_s_barrier();
  asm volatile("" ::: "memory");
#pragma unroll
  for (int m = 0; m < 4; ++m) {
    a[m][0] = ldsf(Ac, m * 32 + wr * 16 + lrow, grp);
    a[m][1] = ldsf(Ac, m * 32 + wr * 16 + lrow, 4 + grp);
  }
#pragma unroll
  for (int n = 0; n < 2; ++n) {
    bx[n][0] = ldsf(Bxc, wc * 32 + n * 16 + lrow, grp);
    bx[n][1] = ldsf(Bxc, wc * 32 + n * 16 + lrow, 4 + grp);
  }
  if constexpr (PF) stage_half(gA + ko, stride, An, wv, lane);
  asm volatile("s_waitcnt lgkmcnt(0)" ::: "memory");
  __builtin_amdgcn_sched_barrier(0);
  __builtin_amdgcn_s_setprio(1);
#pragma unroll
  for (int ks = 0; ks < 2; ++ks)
#pragma unroll
    for (int m = 0; m < 4; ++m)
#pragma unroll
      for (int n = 0; n < 2; ++n)
        accX[m][n] = __builtin_amdgcn_mfma_f32_16x16x32_bf16(a[m][ks], bx[n][ks], accX[m][n], 0, 0, 0);
  __builtin_amdgcn_s_setprio(0);
  // ---- ph1: Y-low | reads By(4) | stage Bx(t+1)
  wait_vm<W1>();
  __builtin_amdgcn_s_barrier();
  asm volatile("" ::: "memory");
#pragma unroll
  for (int n = 0; n < 2; ++n) {
    by[n][0] = ldsf(Byc, wc * 32 + n * 16 + lrow, grp);
    by[n][1] = ldsf(Byc, wc * 32 + n * 16 + lrow, 4 + grp);
  }
  if constexpr (PF) stage_half(gBx + ko, stride, Bxn, wv, lane);
  asm volatile("s_waitcnt lgkmcnt(0)" ::: "memory");
  __builtin_amdgcn_sched_barrier(0);
  __builtin_amdgcn_s_setprio(1);
#pragma unroll
  for (int ks = 0; ks < 2; ++ks)
#pragma unroll
    for (int m = 0; m < 4; ++m)
#pragma unroll
      for (int n = 0; n < 2; ++n)
        accY[m][n] = __builtin_amdgcn_mfma_f32_16x16x32_bf16(a[m][ks], by[n][ks], accY[m][n], 0, 0, 0);
  __builtin_amdgcn_s_setprio(0);
  // ---- ph2: X-high | reads Ahi(8) | stage By(t+1)
  wait_vm<W2>();
  __builtin_amdgcn_s_barrier();
  asm volatile("" ::: "memory");
#pragma unroll
  for (int m = 0; m < 4; ++m) {
    a[m][0] = ldsf(Ac, (m + 4) * 32 + wr * 16 + lrow, grp);
    a[m][1] = ldsf(Ac, (m + 4) * 32 + wr * 16 + lrow, 4 + grp);
  }
  if constexpr (PF) stage_half(gBy + ko, stride, Byn, wv, lane);
  asm volatile("s_waitcnt lgkmcnt(0)" ::: "memory");
  __builtin_amdgcn_sched_barrier(0);
  __builtin_amdgcn_s_setprio(1);
#pragma unroll
  for (int ks = 0; ks < 2; ++ks)
#pragma unroll
    for (int m = 0; m < 4; ++m)
#pragma unroll
      for (int n = 0; n < 2; ++n)
        accX[m + 4][n] = __builtin_amdgcn_mfma_f32_16x16x32_bf16(a[m][ks], bx[n][ks], accX[m + 4][n], 0, 0, 0);
  __builtin_amdgcn_s_setprio(0);
  // ---- ph3: Y-high | no reads | stage Ahi(t+1) (operands all in regs)
  if constexpr (PF) stage_half(gA + 128 * stride + ko, stride, An + 128 * 64, wv, lane);
  __builtin_amdgcn_s_setprio(1);
#pragma unroll
  for (int ks = 0; ks < 2; ++ks)
#pragma unroll
    for (int m = 0; m < 4; ++m)
#pragma unroll
      for (int n = 0; n < 2; ++n)
        accY[m + 4][n] = __builtin_amdgcn_mfma_f32_16x16x32_bf16(a[m][ks], by[n][ks], accY[m + 4][n], 0, 0, 0);
  __builtin_amdgcn_s_setprio(0);
}

// ---------------- GEMM1: 256x128 tile, dual-B (W1,W3) ----------------

__global__ __launch_bounds__(512, 2) void gemm1_kernel(
    const uint16_t* __restrict__ xg, const uint16_t* __restrict__ w1b,
    const uint16_t* __restrict__ w3b, uint16_t* __restrict__ hbuf,
    const int* __restrict__ counters) {
  __shared__ __align__(16) uint16_t lsA[2][256 * 64];    // 64 KB
  __shared__ __align__(16) uint16_t lsB1[2][128 * 64];   // 32 KB
  __shared__ __align__(16) uint16_t lsB3[2][128 * 64];   // 32 KB

  const int c0 = counters[0], c1 = counters[1];
  const int t0 = (c0 + 255) >> 8, t1 = (c1 + 255) >> 8;
  // bijective XCD swizzle (m204): within an XCD chunk rt varies fastest ->
  // the B1/B3 128-col panels stay L2-resident per XCD (R5's measured config).
  const int GX = gridDim.x;
  const int nwg = GX * (int)gridDim.y;
  const int orig = blockIdx.y * GX + blockIdx.x;
  const int q = nwg >> 3, r = nwg & 7;
  const int xcd = orig & 7, loc = orig >> 3;
  const int swz = (xcd < r ? xcd * (q + 1) : r * (q + 1) + (xcd - r) * q) + loc;
  const int ht = swz / GX;
  const int rt = swz - ht * GX;
  if (rt >= t0 + t1) return;
  const int mod = (rt < t0) ? 0 : 1;
  const long row0 = (long)rt * 256;

  const int tid = threadIdx.x, lane = tid & 63, wv = tid >> 6;
  const int wr = wv >> 2, wc = wv & 3;            // 2M x 4N waves
  const int lrow = lane & 15, grp = lane >> 4;

  const uint16_t* gA  = xg  + row0 * DIMK;
  const uint16_t* gB1 = w1b + ((long)mod * HID + ht * 128) * DIMK;
  const uint16_t* gB3 = w3b + ((long)mod * HID + ht * 128) * DIMK;

  f32x4 accG[8][2], accU[8][2];
#pragma unroll
  for (int m = 0; m < 8; ++m)
#pragma unroll
    for (int n = 0; n < 2; ++n) {
      accG[m][n] = {0.f, 0.f, 0.f, 0.f};
      accU[m][n] = {0.f, 0.f, 0.f, 0.f};
    }

  // prologue: tile 0 -> buf 0, in issue order [Alo, B1, B3, Ahi]; no drain.
  stage_half(gA,              DIMK, &lsA[0][0],         wv, lane);
  stage_half(gB1,             DIMK, &lsB1[0][0],        wv, lane);
  stage_half(gB3,             DIMK, &lsB3[0][0],        wv, lane);
  stage_half(gA + 128 * DIMK, DIMK, &lsA[0][128 * 64],  wv, lane);

  const int NT = DIMK / 64;                        // 16
  int cur = 0;
  for (int t = 0; t < NT - 1; ++t) {
    quad_tile<true, 4, 4, 4>(&lsA[cur][0], &lsB1[cur][0], &lsB3[cur][0],
                             &lsA[cur ^ 1][0], &lsB1[cur ^ 1][0], &lsB3[cur ^ 1][0],
                             gA, gB1, gB3, (long)(t + 1) * 64, DIMK,
                             wv, lane, wr, wc, lrow, grp, accG, accU);
    cur ^= 1;
  }
  quad_tile<false, 4, 2, 0>(&lsA[cur][0], &lsB1[cur][0], &lsB3[cur][0],
                            &lsA[cur ^ 1][0], &lsB1[cur ^ 1][0], &lsB3[cur ^ 1][0],
                            gA, gB1, gB3, 0, DIMK,
                            wv, lane, wr, wc, lrow, grp, accG, accU);

  // epilogue: h = silu(x1) * x3 -> bf16 (gap rows harmless, never scattered)
#pragma unroll
  for (int m = 0; m < 8; ++m)
#pragma unroll
    for (int n = 0; n < 2; ++n) {
      const int col = ht * 128 + wc * 32 + n * 16 + lrow;
#pragma unroll
      for (int i = 0; i < 4; ++i) {
        const long row = row0 + m * 32 + wr * 16 + grp * 4 + i;
        float g = accG[m][n][i];
        float u = accU[m][n][i];
        float hv = (g / (1.f + __expf(-g))) * u;
        hbuf[row * HID + col] = f2bf(hv);
      }
    }
}

// ---------------- GEMM2: 256x256 tile via the same quad-tile ----------------
// Bx = W2 rows ct*256..+127, By = rows +128..255; accY cols offset +128.

__global__ __launch_bounds__(512, 2) void gemm2_kernel(
    const uint16_t* __restrict__ hbuf, const uint16_t* __restrict__ w2b,
    const int* __restrict__ counters, const int* __restrict__ tok,
    float* __restrict__ out) {
  __shared__ __align__(16) uint16_t lsA[2][256 * 64];    // 64 KB
  __shared__ __align__(16) uint16_t lsBx[2][128 * 64];   // 32 KB
  __shared__ __align__(16) uint16_t lsBy[2][128 * 64];   // 32 KB

  const int c0 = counters[0], c1 = counters[1];
  const int t0 = (c0 + 255) >> 8, t1 = (c1 + 255) >> 8;
  // rt-major chunks: same-XCD blocks share the A (hbuf) row-tile in L2.
  const int NCT = gridDim.y;                       // 4
  const int nwg = gridDim.x * NCT;
  const int orig = blockIdx.y * gridDim.x + blockIdx.x;
  const int q = nwg >> 3, r = nwg & 7;
  const int xcd = orig & 7, loc = orig >> 3;
  const int swz = (xcd < r ? xcd * (q + 1) : r * (q + 1) + (xcd - r) * q) + loc;
  const int rt = swz / NCT;
  const int ct = swz - rt * NCT;
  if (rt >= t0 + t1) return;
  const int mod = (rt < t0) ? 0 : 1;
  const long row0 = (long)rt * 256;
  const int vlimit = (mod == 0) ? c0 : t0 * 256 + c1;

  const int tid = threadIdx.x, lane = tid & 63, wv = tid >> 6;
  const int wr = wv >> 2, wc = wv & 3;
  const int lrow = lane & 15, grp = lane >> 4;

  const uint16_t* gA  = hbuf + row0 * HID;
  const uint16_t* gBx = w2b + ((long)mod * DIMK + ct * 256) * HID;
  const uint16_t* gBy = gBx + 128 * HID;

  f32x4 accX[8][2], accY[8][2];
#pragma unroll
  for (int m = 0; m < 8; ++m)
#pragma unroll
    for (int n = 0; n < 2; ++n) {
      accX[m][n] = {0.f, 0.f, 0.f, 0.f};
      accY[m][n] = {0.f, 0.f, 0.f, 0.f};
    }

  // prologue: tile 0 -> buf 0, issue order [Alo, Bx, By, Ahi]
  stage_half(gA,             HID, &lsA[0][0],        wv, lane);
  stage_half(gBx,            HID, &lsBx[0][0],       wv, lane);
  stage_half(gBy,            HID, &lsBy[0][0],       wv, lane);
  stage_half(gA + 128 * HID, HID, &lsA[0][128 * 64], wv, lane);

  const int NT = HID / 64;                         // 44
  int cur = 0;
  for (int t = 0; t < NT - 1; ++t) {
    quad_tile<true, 4, 4, 4>(&lsA[cur][0], &lsBx[cur][0], &lsBy[cur][0],
                             &lsA[cur ^ 1][0], &lsBx[cur ^ 1][0], &lsBy[cur ^ 1][0],
                             gA, gBx, gBy, (long)(t + 1) * 64, HID,
                             wv, lane, wr, wc, lrow, grp, accX, accY);
    cur ^= 1;
  }
  quad_tile<false, 4, 2, 0>(&lsA[cur][0], &lsBx[cur][0], &lsBy[cur][0],
                            &lsA[cur ^ 1][0], &lsBx[cur ^ 1][0], &lsBy[cur ^ 1][0],
                            gA, gBx, gBy, 0, HID,
                            wv, lane, wr, wc, lrow, grp, accX, accY);

#pragma unroll
  for (int m = 0; m < 8; ++m)
#pragma unroll
    for (int n = 0; n < 2; ++n) {
      const int colX = ct * 256 + wc * 32 + n * 16 + lrow;
#pragma unroll
      for (int i = 0; i < 4; ++i) {
        const int row = (int)row0 + m * 32 + wr * 16 + grp * 4 + i;
        if (row < vlimit) {
          const long obase = (long)tok[row] * DIMK;
          out[obase + colX]       = accX[m][n][i];
          out[obase + colX + 128] = accY[m][n][i];
        }
      }
    }
}

extern "C" void kernel_launch(void* const* d_in, const int* in_sizes, int n_in,
                              void* d_out, int out_size, void* d_ws, size_t ws_size,
                              hipStream_t stream) {
  const float* x    = (const float*)d_in[0];
  const int*   mids = (const int*)d_in[1];
  const float* W1   = (const float*)d_in[2];
  const float* W2   = (const float*)d_in[3];
  const float* W3   = (const float*)d_in[4];
  float* out = (float*)d_out;

  const int T   = in_sizes[1];                       // 32768 tokens
  const int NB  = (T + 255) / 256;                   // 128 count blocks
  const int CAP = ((T + 255) & ~255) + 256;          // 256-aligned capacity + gap tile

  char* ws = (char*)d_ws;
  int* counters = (int*)ws;                          // [c0, c1]
  int* bc   = (int*)(ws + 256);                      // per-block counts [NB][2]
  int* base = (int*)(ws + 256 + 2048);               // per-block bases  [NB][2]
  int* tok  = (int*)(ws + 256 + 4096);               // slot -> token
  int* slotof = tok + ((CAP + 63) & ~63);            // token -> slot
  size_t off = 256 + 4096 + (size_t)((CAP + 63) & ~63) * 4 + (size_t)((T + 63) & ~63) * 4;
  off = (off + 255) & ~(size_t)255;
  uint16_t* xg  = (uint16_t*)(ws + off); off += (size_t)CAP * DIMK * 2;
  uint16_t* w1b = (uint16_t*)(ws + off); off += (size_t)2 * HID * DIMK * 2;
  uint16_t* w3b = (uint16_t*)(ws + off); off += (size_t)2 * HID * DIMK * 2;
  uint16_t* w2b = (uint16_t*)(ws + off); off += (size_t)2 * DIMK * HID * 2;
  uint16_t* hbuf = (uint16_t*)(ws + off); off += (size_t)CAP * HID * 2;
  (void)ws_size; (void)n_in; (void)out_size;

  count_kernel<<<NB, 256, 0, stream>>>(mids, bc, T);
  scan_kernel<<<1, 256, 0, stream>>>(bc, base, counters, NB);
  slot_kernel<<<NB, 256, 0, stream>>>(mids, base, counters, tok, slotof, T);
  copy_kernel<<<(T + 3) / 4, 256, 0, stream>>>(x, slotof, xg, T);

  const long NW = (long)2 * HID * DIMK;              // elements per weight tensor
  const int cblk = (int)((NW / 4 + 255) / 256);
  convert3_kernel<<<3 * cblk, 256, 0, stream>>>(W1, W3, W2, w1b, w3b, w2b, NW, cblk);

  const int rtiles = CAP / 256;                      // 129
  gemm1_kernel<<<dim3(rtiles, HID / 128), 512, 0, stream>>>(xg, w1b, w3b, hbuf, counters);
  gemm2_kernel<<<dim3(rtiles, DIMK / 256), 512, 0, stream>>>(hbuf, w2b, counters, tok, out);
}